// Round 1
// baseline (316.847 us; speedup 1.0000x reference)
//
#include <hip/hip_runtime.h>

#define B 8
#define N 2048
#define D 64
#define NL 3
#define BN (B*N)
#define CAP 64

// h0 = x @ U0 + b0.  One wave per row; lane = output dim.
__global__ __launch_bounds__(256) void k1_proj(const float* __restrict__ x,
        const float* __restrict__ U0, const float* __restrict__ b0,
        float* __restrict__ h) {
    __shared__ float Uld[D * D];
    __shared__ float bld[D];
    int tid = threadIdx.x;
#pragma unroll
    for (int q = 0; q < 16; ++q) Uld[tid + q * 256] = U0[tid + q * 256];
    if (tid < D) bld[tid] = b0[tid];
    __syncthreads();
    int wid = tid >> 6, lane = tid & 63;
    int r = blockIdx.x * 4 + wid;              // global row in [0, B*N)
    float xv = x[(size_t)r * D + lane];        // coalesced
    float acc = bld[lane];
    for (int k = 0; k < D; ++k) {
        float a = __shfl(xv, k);               // broadcast x[r][k]
        acc = fmaf(a, Uld[k * D + lane], acc);
    }
    h[(size_t)r * D + lane] = acc;
}

// Build per-column neighbor lists (CSC) + degree counts from binary adjacency.
// adj[b, j, i] != 0  ->  append j to column (b,i).  One 128 MB coalesced scan.
__global__ __launch_bounds__(256) void k2_build(const float* __restrict__ adj,
        unsigned short* __restrict__ cols, int* __restrict__ cnt) {
    int i = blockIdx.x * 256 + threadIdx.x;    // column index
    int b = blockIdx.y;
    int j0 = blockIdx.z * (N / 8);             // row chunk for parallelism
    const float* base = adj + (size_t)b * N * N + i;
    int col = b * N + i;
    for (int j = j0; j < j0 + N / 8; ++j) {
        if (base[(size_t)j * N] != 0.0f) {     // coalesced across i
            int p = atomicAdd(&cnt[col], 1);
            if (p < CAP) cols[(size_t)p * BN + col] = (unsigned short)j;
        }
    }
}

// One GCN layer: hout[i,:] = relu( (sum_{j in col(i)} hin[j,:]) @ U / deg[i] )
__global__ __launch_bounds__(256) void k3_layer(const float* __restrict__ hin,
        const unsigned short* __restrict__ cols, const int* __restrict__ cnt,
        const float* __restrict__ U, float* __restrict__ hout) {
    __shared__ float Uld[D * D];
    int tid = threadIdx.x;
#pragma unroll
    for (int q = 0; q < 16; ++q) Uld[tid + q * 256] = U[tid + q * 256];
    __syncthreads();
    int wid = tid >> 6, lane = tid & 63;
    int r = blockIdx.x * 4 + wid;              // global row (b*N + i)
    int b = r >> 11;                           // N = 2048
    int c = cnt[r];
    int kmax = c < CAP ? c : CAP;
    const float* hb = hin + ((size_t)b << 11) * D;
    float acc = 0.f;                           // agg[r][lane]
    for (int k = 0; k < kmax; ++k) {
        int j = cols[(size_t)k * BN + r];      // broadcast read
        acc += hb[(size_t)j * D + lane];       // coalesced 256B row gather (L2-hit)
    }
    float out = 0.f;
    for (int d = 0; d < D; ++d) {
        float a = __shfl(acc, d);              // agg[r][d]
        out = fmaf(a, Uld[d * D + lane], out);
    }
    out = fmaxf(out / (float)c, 0.f);
    hout[(size_t)r * D + lane] = out;
}

// m[b,d] = mean_n h[b,n,d]
__global__ __launch_bounds__(256) void k4_mean(const float* __restrict__ h,
        float* __restrict__ m) {
    __shared__ float part[4][D];
    int tid = threadIdx.x;
    int d = tid & 63, sub = tid >> 6;
    int b = blockIdx.y;
    int r0 = blockIdx.x * 256 + sub * 64;
    const float* hb = h + ((size_t)b * N + r0) * D + d;
    float s = 0.f;
    for (int t = 0; t < 64; ++t) s += hb[(size_t)t * D];
    part[sub][d] = s;
    __syncthreads();
    if (tid < 64) {
        float tot = part[0][tid] + part[1][tid] + part[2][tid] + part[3][tid];
        atomicAdd(&m[b * D + tid], tot * (1.0f / N));
    }
}

// out[b] = P . relu(Q @ m[b])   -- single wave
__global__ void k5_head(const float* __restrict__ m, const float* __restrict__ Q,
        const float* __restrict__ P, float* __restrict__ out) {
    int lane = threadIdx.x;  // 64 threads
    for (int b = 0; b < B; ++b) {
        float t = 0.f;
        for (int k = 0; k < D; ++k) t = fmaf(Q[lane * D + k], m[b * D + k], t);
        t = fmaxf(t, 0.f);
        float v = t * P[lane];
        for (int off = 32; off; off >>= 1) v += __shfl_down(v, off);
        if (lane == 0) out[b] = v;
    }
}

extern "C" void kernel_launch(void* const* d_in, const int* in_sizes, int n_in,
                              void* d_out, int out_size, void* d_ws, size_t ws_size,
                              hipStream_t stream) {
    const float* x   = (const float*)d_in[0];
    const float* adj = (const float*)d_in[1];
    const float* U0  = (const float*)d_in[2];
    const float* b0  = (const float*)d_in[3];
    const float* Us  = (const float*)d_in[4];
    const float* Q   = (const float*)d_in[5];
    const float* P   = (const float*)d_in[6];
    float* out = (float*)d_out;

    char* ws = (char*)d_ws;
    size_t off = 0;
    float* h0 = (float*)(ws + off); off += (size_t)BN * D * sizeof(float);  // 4 MB
    float* h1 = (float*)(ws + off); off += (size_t)BN * D * sizeof(float);  // 4 MB
    unsigned short* cols = (unsigned short*)(ws + off);
    off += (size_t)CAP * BN * sizeof(unsigned short);                       // 2 MB
    int* cnt = (int*)(ws + off); off += (size_t)BN * sizeof(int);           // 64 KB
    float* m = (float*)(ws + off); off += (size_t)B * D * sizeof(float);    // 2 KB

    hipMemsetAsync(cnt, 0, (size_t)BN * sizeof(int), stream);
    hipMemsetAsync(m, 0, (size_t)B * D * sizeof(float), stream);

    k1_proj<<<BN / 4, 256, 0, stream>>>(x, U0, b0, h0);
    k2_build<<<dim3(N / 256, B, 8), 256, 0, stream>>>(adj, cols, cnt);
    k3_layer<<<BN / 4, 256, 0, stream>>>(h0, cols, cnt, Us + 0 * D * D, h1);
    k3_layer<<<BN / 4, 256, 0, stream>>>(h1, cols, cnt, Us + 1 * D * D, h0);
    k3_layer<<<BN / 4, 256, 0, stream>>>(h0, cols, cnt, Us + 2 * D * D, h1);
    k4_mean<<<dim3(N / 256, B), 256, 0, stream>>>(h1, m);
    k5_head<<<1, 64, 0, stream>>>(m, Q, P, out);
}

// Round 2
// 175.043 us; speedup vs baseline: 1.8101x; 1.8101x over previous
//
#include <hip/hip_runtime.h>

#define B 8
#define N 2048
#define D 64
#define BN (B*N)
#define CAP 64

// h0 = x @ U0 + b0.  One wave per row; lane = output dim.
__global__ __launch_bounds__(256) void k1_proj(const float* __restrict__ x,
        const float* __restrict__ U0, const float* __restrict__ b0,
        float* __restrict__ h) {
    __shared__ float Uld[D * D];
    __shared__ float bld[D];
    int tid = threadIdx.x;
#pragma unroll
    for (int q = 0; q < 16; ++q) Uld[tid + q * 256] = U0[tid + q * 256];
    if (tid < D) bld[tid] = b0[tid];
    __syncthreads();
    int wid = tid >> 6, lane = tid & 63;
    int r = blockIdx.x * 4 + wid;              // global row in [0, B*N)
    float xv = x[(size_t)r * D + lane];        // coalesced
    float acc = bld[lane];
#pragma unroll 8
    for (int k = 0; k < D; ++k) {
        float a = __shfl(xv, k);               // broadcast x[r][k]
        acc = fmaf(a, Uld[k * D + lane], acc);
    }
    h[(size_t)r * D + lane] = acc;
}

// Build per-column neighbor lists (CSC, [col][CAP] layout) + degree counts.
// float4 loads, 4 columns/thread, deep unroll for outstanding loads.
__global__ __launch_bounds__(256) void k2_build(const float* __restrict__ adj,
        unsigned short* __restrict__ cols, int* __restrict__ cnt) {
    int i0 = (blockIdx.x * 256 + threadIdx.x) * 4;   // first of 4 columns
    int b = blockIdx.y;
    int j0 = blockIdx.z * 32;                        // 32-row j chunk
    const float* base = adj + (size_t)b * N * N + i0;
    int colb = b * N + i0;
#pragma unroll 8
    for (int j = j0; j < j0 + 32; ++j) {
        float4 v = *(const float4*)(base + (size_t)j * N);
        if (v.x + v.y + v.z + v.w != 0.0f) {         // values are {0,1}
            if (v.x != 0.f) { int p = atomicAdd(&cnt[colb+0], 1); if (p < CAP) cols[(size_t)(colb+0)*CAP + p] = (unsigned short)j; }
            if (v.y != 0.f) { int p = atomicAdd(&cnt[colb+1], 1); if (p < CAP) cols[(size_t)(colb+1)*CAP + p] = (unsigned short)j; }
            if (v.z != 0.f) { int p = atomicAdd(&cnt[colb+2], 1); if (p < CAP) cols[(size_t)(colb+2)*CAP + p] = (unsigned short)j; }
            if (v.w != 0.f) { int p = atomicAdd(&cnt[colb+3], 1); if (p < CAP) cols[(size_t)(colb+3)*CAP + p] = (unsigned short)j; }
        }
    }
}

// One GCN layer: hout[i,:] = relu( (sum_{j in col(i)} hin[j,:]) @ U / deg[i] )
__global__ __launch_bounds__(256) void k3_layer(const float* __restrict__ hin,
        const unsigned short* __restrict__ cols, const int* __restrict__ cnt,
        const float* __restrict__ U, float* __restrict__ hout) {
    __shared__ float Uld[D * D];
    int tid = threadIdx.x;
#pragma unroll
    for (int q = 0; q < 16; ++q) Uld[tid + q * 256] = U[tid + q * 256];
    __syncthreads();
    int wid = tid >> 6, lane = tid & 63;
    int r = blockIdx.x * 4 + wid;              // global row (b*N + i)
    int b = r >> 11;                           // N = 2048
    int c = cnt[r];
    int kmax = c < CAP ? c : CAP;
    const float* hb = hin + ((size_t)b << 11) * D;
    const unsigned short* cl = cols + (size_t)r * CAP;
    float acc = 0.f;                           // agg[r][lane]
    int k = 0;
    for (; k + 4 <= kmax; k += 4) {            // 4 indices per load -> 4 gathers in flight
        ushort4 j4 = *(const ushort4*)(cl + k);
        float a0 = hb[(size_t)j4.x * D + lane];
        float a1 = hb[(size_t)j4.y * D + lane];
        float a2 = hb[(size_t)j4.z * D + lane];
        float a3 = hb[(size_t)j4.w * D + lane];
        acc += (a0 + a1) + (a2 + a3);
    }
    for (; k < kmax; ++k) acc += hb[(size_t)cl[k] * D + lane];
    float out = 0.f;
#pragma unroll 8
    for (int d = 0; d < D; ++d) {
        float a = __shfl(acc, d);              // agg[r][d]
        out = fmaf(a, Uld[d * D + lane], out);
    }
    out = fmaxf(out / (float)c, 0.f);
    hout[(size_t)r * D + lane] = out;
}

// m[b,d] = mean_n h[b,n,d]
__global__ __launch_bounds__(256) void k4_mean(const float* __restrict__ h,
        float* __restrict__ m) {
    __shared__ float part[4][D];
    int tid = threadIdx.x;
    int d = tid & 63, sub = tid >> 6;
    int b = blockIdx.y;
    int r0 = blockIdx.x * 256 + sub * 64;
    const float* hb = h + ((size_t)b * N + r0) * D + d;
    float s = 0.f;
#pragma unroll 4
    for (int t = 0; t < 64; ++t) s += hb[(size_t)t * D];
    part[sub][d] = s;
    __syncthreads();
    if (tid < 64) {
        float tot = part[0][tid] + part[1][tid] + part[2][tid] + part[3][tid];
        atomicAdd(&m[b * D + tid], tot * (1.0f / N));
    }
}

// out[b] = P . relu(Q @ m[b])   -- single wave
__global__ void k5_head(const float* __restrict__ m, const float* __restrict__ Q,
        const float* __restrict__ P, float* __restrict__ out) {
    int lane = threadIdx.x;  // 64 threads
    for (int b = 0; b < B; ++b) {
        float t = 0.f;
        for (int k = 0; k < D; ++k) t = fmaf(Q[lane * D + k], m[b * D + k], t);
        t = fmaxf(t, 0.f);
        float v = t * P[lane];
        for (int off = 32; off; off >>= 1) v += __shfl_down(v, off);
        if (lane == 0) out[b] = v;
    }
}

extern "C" void kernel_launch(void* const* d_in, const int* in_sizes, int n_in,
                              void* d_out, int out_size, void* d_ws, size_t ws_size,
                              hipStream_t stream) {
    const float* x   = (const float*)d_in[0];
    const float* adj = (const float*)d_in[1];
    const float* U0  = (const float*)d_in[2];
    const float* b0  = (const float*)d_in[3];
    const float* Us  = (const float*)d_in[4];
    const float* Q   = (const float*)d_in[5];
    const float* P   = (const float*)d_in[6];
    float* out = (float*)d_out;

    char* ws = (char*)d_ws;
    size_t off = 0;
    float* h0 = (float*)(ws + off); off += (size_t)BN * D * sizeof(float);  // 4 MB
    float* h1 = (float*)(ws + off); off += (size_t)BN * D * sizeof(float);  // 4 MB
    unsigned short* cols = (unsigned short*)(ws + off);
    off += (size_t)CAP * BN * sizeof(unsigned short);                       // 2 MB
    int* cnt = (int*)(ws + off); off += (size_t)BN * sizeof(int);           // 64 KB
    float* m = (float*)(ws + off); off += (size_t)B * D * sizeof(float);    // 2 KB

    hipMemsetAsync(cnt, 0, (size_t)BN * sizeof(int), stream);
    hipMemsetAsync(m, 0, (size_t)B * D * sizeof(float), stream);

    k1_proj<<<BN / 4, 256, 0, stream>>>(x, U0, b0, h0);
    k2_build<<<dim3(N / 1024, B, N / 32), 256, 0, stream>>>(adj, cols, cnt);
    k3_layer<<<BN / 4, 256, 0, stream>>>(h0, cols, cnt, Us + 0 * D * D, h1);
    k3_layer<<<BN / 4, 256, 0, stream>>>(h1, cols, cnt, Us + 1 * D * D, h0);
    k3_layer<<<BN / 4, 256, 0, stream>>>(h0, cols, cnt, Us + 2 * D * D, h1);
    k4_mean<<<dim3(N / 256, B), 256, 0, stream>>>(h1, m);
    k5_head<<<1, 64, 0, stream>>>(m, Q, P, out);
}

// Round 3
// 166.086 us; speedup vs baseline: 1.9077x; 1.0539x over previous
//
#include <hip/hip_runtime.h>

#define B 8
#define N 2048
#define D 64
#define BN (B*N)
#define CAP 64
#define NW 64          // 64 u32 words = 2048 bits per column

// h0 = x @ U0 + b0.  One wave per row; lane = output dim.
__global__ __launch_bounds__(256) void k1_proj(const float* __restrict__ x,
        const float* __restrict__ U0, const float* __restrict__ b0,
        float* __restrict__ h) {
    __shared__ float Uld[D * D];
    __shared__ float bld[D];
    int tid = threadIdx.x;
#pragma unroll
    for (int q = 0; q < 16; ++q) Uld[tid + q * 256] = U0[tid + q * 256];
    if (tid < D) bld[tid] = b0[tid];
    __syncthreads();
    int wid = tid >> 6, lane = tid & 63;
    int r = blockIdx.x * 4 + wid;              // global row in [0, B*N)
    float xv = x[(size_t)r * D + lane];        // coalesced
    float acc = bld[lane];
#pragma unroll 8
    for (int k = 0; k < D; ++k) {
        float a = __shfl(xv, k);               // broadcast x[r][k]
        acc = fmaf(a, Uld[k * D + lane], acc);
    }
    h[(size_t)r * D + lane] = acc;
}

// Branch-free, atomic-free 128 MB scan: adjacency -> bitmasks.
// masks[w][col] (u32): bit jj set iff adj[b][w*32+jj][i] != 0, col = b*N+i.
__global__ __launch_bounds__(256) void k2a_scan(const float* __restrict__ adj,
        unsigned* __restrict__ masks) {
    int i0 = (blockIdx.x * 256 + threadIdx.x) * 4;   // 4 adjacent columns
    int b = blockIdx.y;
    int w = blockIdx.z;                              // word index [0, NW)
    const float* base = adj + (size_t)b * N * N + (size_t)(w * 32) * N + i0;
    unsigned m0 = 0, m1 = 0, m2 = 0, m3 = 0;
#pragma unroll 8
    for (int jj = 0; jj < 32; ++jj) {
        float4 v = *(const float4*)(base + (size_t)jj * N);
        m0 |= (v.x != 0.f ? 1u : 0u) << jj;
        m1 |= (v.y != 0.f ? 1u : 0u) << jj;
        m2 |= (v.z != 0.f ? 1u : 0u) << jj;
        m3 |= (v.w != 0.f ? 1u : 0u) << jj;
    }
    unsigned* dst = masks + (size_t)w * BN + b * N + i0;
    dst[0] = m0; dst[1] = m1; dst[2] = m2; dst[3] = m3;
}

// masks -> per-column neighbor lists ([col][CAP]) + exact degree. 4 MB pass.
__global__ __launch_bounds__(256) void k2b_lists(const unsigned* __restrict__ masks,
        unsigned short* __restrict__ cols, int* __restrict__ cnt) {
    int col = blockIdx.x * 256 + threadIdx.x;        // one thread per column
    unsigned short* cl = cols + (size_t)col * CAP;
    int p = 0;
    for (int w = 0; w < NW; ++w) {
        unsigned m = masks[(size_t)w * BN + col];    // coalesced across lanes
        int jb = w * 32;
        while (m) {
            int t = __builtin_ctz(m);
            m &= m - 1;
            if (p < CAP) cl[p] = (unsigned short)(jb + t);
            ++p;
        }
    }
    cnt[col] = p;
}

// One GCN layer: hout[i,:] = relu( (sum_{j in col(i)} hin[j,:]) @ U / deg[i] )
__global__ __launch_bounds__(256) void k3_layer(const float* __restrict__ hin,
        const unsigned short* __restrict__ cols, const int* __restrict__ cnt,
        const float* __restrict__ U, float* __restrict__ hout) {
    __shared__ float Uld[D * D];
    int tid = threadIdx.x;
#pragma unroll
    for (int q = 0; q < 16; ++q) Uld[tid + q * 256] = U[tid + q * 256];
    __syncthreads();
    int wid = tid >> 6, lane = tid & 63;
    int r = blockIdx.x * 4 + wid;              // global row (b*N + i)
    int b = r >> 11;                           // N = 2048
    int c = cnt[r];
    int kmax = c < CAP ? c : CAP;
    const float* hb = hin + ((size_t)b << 11) * D;
    const unsigned short* cl = cols + (size_t)r * CAP;
    float acc = 0.f;                           // agg[r][lane]
    int k = 0;
    for (; k + 4 <= kmax; k += 4) {            // 4 indices per load -> 4 gathers in flight
        ushort4 j4 = *(const ushort4*)(cl + k);
        float a0 = hb[(size_t)j4.x * D + lane];
        float a1 = hb[(size_t)j4.y * D + lane];
        float a2 = hb[(size_t)j4.z * D + lane];
        float a3 = hb[(size_t)j4.w * D + lane];
        acc += (a0 + a1) + (a2 + a3);
    }
    for (; k < kmax; ++k) acc += hb[(size_t)cl[k] * D + lane];
    float out = 0.f;
#pragma unroll 8
    for (int d = 0; d < D; ++d) {
        float a = __shfl(acc, d);              // agg[r][d]
        out = fmaf(a, Uld[d * D + lane], out);
    }
    out = fmaxf(out / (float)c, 0.f);
    hout[(size_t)r * D + lane] = out;
}

// m[b,d] = mean_n h[b,n,d]
__global__ __launch_bounds__(256) void k4_mean(const float* __restrict__ h,
        float* __restrict__ m) {
    __shared__ float part[4][D];
    int tid = threadIdx.x;
    int d = tid & 63, sub = tid >> 6;
    int b = blockIdx.y;
    int r0 = blockIdx.x * 256 + sub * 64;
    const float* hb = h + ((size_t)b * N + r0) * D + d;
    float s = 0.f;
#pragma unroll 4
    for (int t = 0; t < 64; ++t) s += hb[(size_t)t * D];
    part[sub][d] = s;
    __syncthreads();
    if (tid < 64) {
        float tot = part[0][tid] + part[1][tid] + part[2][tid] + part[3][tid];
        atomicAdd(&m[b * D + tid], tot * (1.0f / N));
    }
}

// out[b] = P . relu(Q @ m[b])   -- single wave
__global__ void k5_head(const float* __restrict__ m, const float* __restrict__ Q,
        const float* __restrict__ P, float* __restrict__ out) {
    int lane = threadIdx.x;  // 64 threads
    for (int b = 0; b < B; ++b) {
        float t = 0.f;
        for (int k = 0; k < D; ++k) t = fmaf(Q[lane * D + k], m[b * D + k], t);
        t = fmaxf(t, 0.f);
        float v = t * P[lane];
        for (int off = 32; off; off >>= 1) v += __shfl_down(v, off);
        if (lane == 0) out[b] = v;
    }
}

extern "C" void kernel_launch(void* const* d_in, const int* in_sizes, int n_in,
                              void* d_out, int out_size, void* d_ws, size_t ws_size,
                              hipStream_t stream) {
    const float* x   = (const float*)d_in[0];
    const float* adj = (const float*)d_in[1];
    const float* U0  = (const float*)d_in[2];
    const float* b0  = (const float*)d_in[3];
    const float* Us  = (const float*)d_in[4];
    const float* Q   = (const float*)d_in[5];
    const float* P   = (const float*)d_in[6];
    float* out = (float*)d_out;

    char* ws = (char*)d_ws;
    size_t off = 0;
    float* h0 = (float*)(ws + off); off += (size_t)BN * D * sizeof(float);  // 4 MB
    float* h1 = (float*)(ws + off); off += (size_t)BN * D * sizeof(float);  // 4 MB
    unsigned short* cols = (unsigned short*)(ws + off);
    off += (size_t)CAP * BN * sizeof(unsigned short);                       // 2 MB
    int* cnt = (int*)(ws + off); off += (size_t)BN * sizeof(int);           // 64 KB
    float* m = (float*)(ws + off); off += (size_t)B * D * sizeof(float);    // 2 KB

    // masks alias h1 (4 MB): consumed by k2b before layer 0 writes h1.
    unsigned* masks = (unsigned*)h1;

    hipMemsetAsync(m, 0, (size_t)B * D * sizeof(float), stream);

    k2a_scan<<<dim3(N / 1024, B, NW), 256, 0, stream>>>(adj, masks);
    k2b_lists<<<BN / 256, 256, 0, stream>>>(masks, cols, cnt);
    k1_proj<<<BN / 4, 256, 0, stream>>>(x, U0, b0, h0);
    k3_layer<<<BN / 4, 256, 0, stream>>>(h0, cols, cnt, Us + 0 * D * D, h1);
    k3_layer<<<BN / 4, 256, 0, stream>>>(h1, cols, cnt, Us + 1 * D * D, h0);
    k3_layer<<<BN / 4, 256, 0, stream>>>(h0, cols, cnt, Us + 2 * D * D, h1);
    k4_mean<<<dim3(N / 256, B), 256, 0, stream>>>(h1, m);
    k5_head<<<1, 64, 0, stream>>>(m, Q, P, out);
}